// Round 1
// baseline (16.937 us; speedup 1.0000x reference)
//
#include <hip/hip_runtime.h>

// MarginRankingLoss over all B*B pairs.
// Key simplification: loss[m,n] = max(0, BIAS - 0.5*(w_m+w_n)*|p_m-p_n|)
// (the gt tie-break only affects r when diff==0, where r*diff==0 anyway;
//  sign flips are exact in IEEE so this is per-pair bit-equivalent).

#define BIAS_F 0.1f

constexpr int TPB = 256;      // threads per block
constexpr int NPT = 8;        // n-values per thread (kept in registers)
constexpr int TN  = TPB * NPT; // 2048 n per block
constexpr int TM  = 32;       // m per block (uniform scalar loads)

__global__ __launch_bounds__(TPB) void pair_loss_kernel(
    const float* __restrict__ pred,
    const float* __restrict__ weight,
    float* __restrict__ partial,
    int B)
{
    const int n_base = blockIdx.x * TN;
    const int m_base = blockIdx.y * TM;
    const int t = threadIdx.x;

    // Per-thread n-data in registers. mask[j] handles any n tail (B%TN==0 here).
    float pn[NPT], wnh[NPT], mask[NPT];
    #pragma unroll
    for (int j = 0; j < NPT; ++j) {
        int n = n_base + j * TPB + t;
        bool ok = (n < B);
        int nc = ok ? n : 0;
        pn[j]   = pred[nc];
        wnh[j]  = weight[nc] * 0.5f;
        mask[j] = ok ? 1.0f : 0.0f;
    }

    float acc[NPT];
    #pragma unroll
    for (int j = 0; j < NPT; ++j) acc[j] = 0.0f;

    const int m_end = (m_base + TM <= B) ? TM : (B - m_base);
    #pragma unroll 4
    for (int i = 0; i < m_end; ++i) {
        const int m = m_base + i;
        const float pm  = pred[m];          // uniform -> scalar load
        const float wmh = weight[m] * 0.5f; // uniform
        #pragma unroll
        for (int j = 0; j < NPT; ++j) {
            float d  = pm - pn[j];
            float w  = wmh + wnh[j];
            float th = fmaf(-w, fabsf(d), BIAS_F); // BIAS - w*|d|
            acc[j] += fmaxf(th, 0.0f);
        }
    }

    float s = 0.0f;
    #pragma unroll
    for (int j = 0; j < NPT; ++j) s += mask[j] * acc[j];

    // wave (64-lane) reduction
    #pragma unroll
    for (int off = 32; off > 0; off >>= 1)
        s += __shfl_down(s, off, 64);

    __shared__ float lds[TPB / 64];
    const int lane = t & 63, wid = t >> 6;
    if (lane == 0) lds[wid] = s;
    __syncthreads();
    if (t == 0) {
        float bs = 0.0f;
        #pragma unroll
        for (int w = 0; w < TPB / 64; ++w) bs += lds[w];
        partial[blockIdx.y * gridDim.x + blockIdx.x] = bs;
    }
}

__global__ __launch_bounds__(256) void reduce_kernel(
    const float* __restrict__ partial, int n, float* __restrict__ out, int B)
{
    double s = 0.0;
    for (int i = threadIdx.x; i < n; i += 256) s += (double)partial[i];
    #pragma unroll
    for (int off = 32; off > 0; off >>= 1)
        s += __shfl_down(s, off, 64);
    __shared__ double lds[4];
    const int lane = threadIdx.x & 63, wid = threadIdx.x >> 6;
    if (lane == 0) lds[wid] = s;
    __syncthreads();
    if (threadIdx.x == 0) {
        double tot = lds[0] + lds[1] + lds[2] + lds[3];
        double inv = 1.0 / ((double)B * (double)B);
        out[0] = (float)(tot * inv);
    }
}

extern "C" void kernel_launch(void* const* d_in, const int* in_sizes, int n_in,
                              void* d_out, int out_size, void* d_ws, size_t ws_size,
                              hipStream_t stream) {
    const float* pred   = (const float*)d_in[0];
    // d_in[1] = correct_output — mathematically irrelevant (see header comment)
    const float* weight = (const float*)d_in[2];
    float* out = (float*)d_out;
    const int B = in_sizes[0];

    const int tilesN = (B + TN - 1) / TN;  // 4 at B=8192
    const int tilesM = (B + TM - 1) / TM;  // 256 at B=8192
    float* partial = (float*)d_ws;         // tilesN*tilesM floats (4 KB)

    dim3 grid(tilesN, tilesM);
    pair_loss_kernel<<<grid, TPB, 0, stream>>>(pred, weight, partial, B);
    reduce_kernel<<<1, 256, 0, stream>>>(partial, tilesN * tilesM, out, B);
}